// Round 18
// baseline (920.031 us; speedup 1.0000x reference)
//
#include <hip/hip_runtime.h>
#include <hip/hip_fp16.h>

#define NN 200000
#define NE 400000
#define DD 128
#define NL 5
#define AV 100
#define BV 10
#define EPSV 1e-5f
#define SCAN_BLKS 196   // ceil(NN/1024)

typedef short s8v __attribute__((ext_vector_type(8)));   // 8 bf16/fp16 (4 VGPRs)
typedef float f4v __attribute__((ext_vector_type(4)));   // 4 fp32 acc

__device__ __forceinline__ ushort f2bf(float f) {        // RNE float->bf16
  uint u = __float_as_uint(f);
  u += 0x7FFFu + ((u >> 16) & 1u);
  return (ushort)(u >> 16);
}

__device__ __forceinline__ float bf2f(ushort u) {        // bf16->float
  return __uint_as_float(((uint)u) << 16);
}

__device__ __forceinline__ ushort f2h(float f) {         // RNE float->fp16
  return __half_as_ushort(__float2half(f));
}

__device__ __forceinline__ float h2f(ushort u) {         // fp16->float
  return __half2float(__ushort_as_half(u));
}

// ---------- atom table -> bf16 (halves encode's L2 stream) ----------
__global__ __launch_bounds__(256) void k_atc(const float* __restrict__ at,
    ushort* __restrict__ atb) {
  int i = blockIdx.x * 256 + threadIdx.x;         // 9*100*128 = 115200 exact
  atb[i] = f2bf(at[i]);
}

// ---------- encode: h = sum of atom embeddings -> acts slot 0 (bf16) ----------
// HALF-wave (32 lanes) per node, 4 dims/lane via ushort4 (8B) gathers from the
// bf16 table.
__global__ __launch_bounds__(256) void k_encode(const int* __restrict__ x,
    const ushort* __restrict__ atb, ushort* __restrict__ hbuf) {
  int idx = blockIdx.x * 256 + threadIdx.x;       // N*32 threads: grid 25000 exact
  int n = idx >> 5, dp = idx & 31;                // half-wave = one node
  const int* xr = x + n * 9;
  float s0 = 0.f, s1 = 0.f, s2 = 0.f, s3 = 0.f;
#pragma unroll
  for (int c = 0; c < 9; ++c) {
    ushort4 v = *(const ushort4*)&atb[(c * AV + xr[c]) * DD + dp * 4];
    s0 += bf2f(v.x); s1 += bf2f(v.y); s2 += bf2f(v.z); s3 += bf2f(v.w);
  }
  ushort4 o;
  o.x = f2bf(s0); o.y = f2bf(s1); o.z = f2bf(s2); o.w = f2bf(s3);
  *(ushort4*)&hbuf[(long)n * DD + dp * 4] = o;
}

// ---------- degree ----------
__global__ __launch_bounds__(256) void k_deg_init(float* __restrict__ deg,
                                                  int* __restrict__ cnt) {
  int i = blockIdx.x * 256 + threadIdx.x;
  if (i < NN) { deg[i] = 1.0f; cnt[i] = 0; }
}

__global__ __launch_bounds__(256) void k_deg_count(const int* __restrict__ ei,
    float* __restrict__ deg, int* __restrict__ cnt) {
  int e = blockIdx.x * 256 + threadIdx.x;
  if (e < NE) {
    atomicAdd(&deg[ei[e]], 1.0f);
    atomicAdd(&cnt[ei[NE + e]], 1);
  }
}

__global__ __launch_bounds__(256) void k_deg_fin(const float* __restrict__ deg,
    float* __restrict__ dis, float* __restrict__ invd) {
  int i = blockIdx.x * 256 + threadIdx.x;
  if (i < NN) {
    float dg = deg[i];
    dis[i] = rsqrtf(dg);
    invd[i] = 1.0f / dg;
  }
}

// ---------- exclusive scan of cnt -> off ----------
__global__ __launch_bounds__(256) void k_scan1(const int* __restrict__ cnt,
    int* __restrict__ off, int* __restrict__ bsum) {
  __shared__ int s[256];
  int t = threadIdx.x;
  int base = blockIdx.x * 1024 + t * 4;
  int c0 = (base + 0 < NN) ? cnt[base + 0] : 0;
  int c1 = (base + 1 < NN) ? cnt[base + 1] : 0;
  int c2 = (base + 2 < NN) ? cnt[base + 2] : 0;
  int c3 = (base + 3 < NN) ? cnt[base + 3] : 0;
  int tsum = c0 + c1 + c2 + c3;
  s[t] = tsum;
  __syncthreads();
  for (int o = 1; o < 256; o <<= 1) {
    int v = (t >= o) ? s[t - o] : 0;
    __syncthreads();
    s[t] += v;
    __syncthreads();
  }
  int excl = s[t] - tsum;
  if (base + 0 < NN) off[base + 0] = excl;
  if (base + 1 < NN) off[base + 1] = excl + c0;
  if (base + 2 < NN) off[base + 2] = excl + c0 + c1;
  if (base + 3 < NN) off[base + 3] = excl + c0 + c1 + c2;
  if (t == 255) bsum[blockIdx.x] = s[255];
}

__global__ __launch_bounds__(256) void k_scan2(const int* __restrict__ bsum,
    int* __restrict__ bbase) {
  __shared__ int s[256];
  int t = threadIdx.x;
  int v0 = (t < SCAN_BLKS) ? bsum[t] : 0;
  s[t] = v0;
  __syncthreads();
  for (int o = 1; o < 256; o <<= 1) {
    int v = (t >= o) ? s[t - o] : 0;
    __syncthreads();
    s[t] += v;
    __syncthreads();
  }
  if (t < SCAN_BLKS) bbase[t] = s[t] - v0;
}

__global__ __launch_bounds__(256) void k_scan3(int* __restrict__ off,
    const int* __restrict__ bbase, int* __restrict__ nxt) {
  int i = blockIdx.x * 256 + threadIdx.x;
  if (i < NN) {
    int v = off[i] + bbase[i >> 10];
    off[i] = v;
    nxt[i] = v;
  }
  if (i == 0) off[NN] = NE;
}

// ---------- fill CSR records: {row, packed_ea, norm_bits, 0} ----------
__global__ __launch_bounds__(256) void k_fill(const int* __restrict__ ei,
    const int* __restrict__ ea, const float* __restrict__ dis,
    int* __restrict__ nxt, int4* __restrict__ recs) {
  int e = blockIdx.x * 256 + threadIdx.x;
  if (e >= NE) return;
  int r = ei[e], c = ei[NE + e];
  int pa = ea[e * 3 + 0] + ea[e * 3 + 1] * 10 + ea[e * 3 + 2] * 100;
  float nr = dis[r] * dis[c];
  int pos = atomicAdd(&nxt[c], 1);
  recs[pos] = make_int4(r, pa, __float_as_int(nr), 0);
}

// ---------- combined bond table (BF16): btc[pa][d] ----------
__global__ __launch_bounds__(256) void k_btc(const float* __restrict__ bt,
    ushort* __restrict__ btc) {
  int idx = blockIdx.x * 256 + threadIdx.x;       // 1000*128 exact
  int p = idx >> 7, d = idx & 127;
  int a = p % 10, b = (p / 10) % 10, c = p / 100;
  btc[idx] = f2bf(bt[(0 * BV + a) * DD + d] + bt[(1 * BV + b) * DD + d]
                + bt[(2 * BV + c) * DD + d]);
}

// ---------- W -> bf16 ----------
__global__ __launch_bounds__(256) void k_wconv(const float* __restrict__ W,
    ushort* __restrict__ Wbf) {
  int i = blockIdx.x * 256 + threadIdx.x;         // 5*128*128 exact
  Wbf[i] = f2bf(W[i]);
}

// ---------- MFMA GEMM: hl(BF16) = A' @ Wl^T + bl ----------
// mode0: A' = srcbf (bf16 h from encode, = acts slot 0).
// mode1: A' = relu(pre_fp16*scale+shift); A' (bf16) stored to actl.
// mode2: like mode1 but folds the h still in actl: store bf16(h + A').
// pre is FP16; BN fold in-kernel from the PREVIOUS layer's stat slice.
__global__ __launch_bounds__(256) void k_gemm(const ushort* __restrict__ srcbf,
    const ushort* __restrict__ srcp, const ushort* __restrict__ Wbf,
    const float* __restrict__ bl, const float* __restrict__ gsum,
    const float* __restrict__ gss, const float* __restrict__ gmm,
    const float* __restrict__ bbn, ushort* __restrict__ actl,
    ushort* __restrict__ hl, int mode) {
  __shared__ float s_sc[DD], s_sh[DD];
  int t = threadIdx.x;
  int lane = t & 63, wave = t >> 6;
  int col = lane & 15, quad = lane >> 4;
  int nb = blockIdx.x * 128 + wave * 32;
  int r0 = nb + col, r1 = nb + 16 + col;
  bool v0 = r0 < NN, v1 = r1 < NN;
  long a0off = (long)(v0 ? r0 : NN - 1) * DD;
  long a1off = (long)(v1 ? r1 : NN - 1) * DD;

  s8v af0[4], af1[4];                             // A fragments, 4 k-slices

  if (mode == 0) {
#pragma unroll
    for (int ks = 0; ks < 4; ++ks) {              // 8 loads, one burst
      int k0 = ks * 32 + quad * 8;
      af0[ks] = *(const s8v*)&srcbf[a0off + k0];
      af1[ks] = *(const s8v*)&srcbf[a1off + k0];
    }
  } else {
    if (t < DD) {                                 // BN fold: stats -> scale/shift
      float m = gsum[t] * (1.0f / NN);
      float v = gss[t] * (1.0f / NN) - m * m;
      float sc = gmm[t] * rsqrtf(v + EPSV);
      s_sc[t] = sc;
      s_sh[t] = bbn[t] - m * sc;
    }
    __syncthreads();
    s8v pF0[4], pF1[4];                           // fp16 pre, one burst (8 loads)
#pragma unroll
    for (int ks = 0; ks < 4; ++ks) {
      int k0 = ks * 32 + quad * 8;
      pF0[ks] = *(const s8v*)&srcp[a0off + k0];
      pF1[ks] = *(const s8v*)&srcp[a1off + k0];
    }
#pragma unroll
    for (int ks = 0; ks < 4; ++ks) {              // activation + pack (VALU)
      int k0 = ks * 32 + quad * 8;
      float scv[8], shv[8];
#pragma unroll
      for (int j = 0; j < 8; ++j) { scv[j] = s_sc[k0 + j]; shv[j] = s_sh[k0 + j]; }
#pragma unroll
      for (int j = 0; j < 8; ++j) {
        float w = fmaxf(h2f((ushort)pF0[ks][j]) * scv[j] + shv[j], 0.f);
        af0[ks][j] = (short)f2bf(w);
        float u = fmaxf(h2f((ushort)pF1[ks][j]) * scv[j] + shv[j], 0.f);
        af1[ks][j] = (short)f2bf(u);
      }
    }
    // store A' (bf16); mode2 folds the h currently in actl
    if (v0) {
#pragma unroll
      for (int ks = 0; ks < 4; ++ks) {
        int k0 = ks * 32 + quad * 8;
        s8v st = af0[ks];
        if (mode == 2) {
          s8v h8 = *(const s8v*)&actl[a0off + k0];
#pragma unroll
          for (int j = 0; j < 8; ++j)
            st[j] = (short)f2bf(bf2f((ushort)h8[j]) + bf2f((ushort)af0[ks][j]));
        }
        *(s8v*)&actl[a0off + k0] = st;
      }
    }
    if (v1) {
#pragma unroll
      for (int ks = 0; ks < 4; ++ks) {
        int k0 = ks * 32 + quad * 8;
        s8v st = af1[ks];
        if (mode == 2) {
          s8v h8 = *(const s8v*)&actl[a1off + k0];
#pragma unroll
          for (int j = 0; j < 8; ++j)
            st[j] = (short)f2bf(bf2f((ushort)h8[j]) + bf2f((ushort)af1[ks][j]));
        }
        *(s8v*)&actl[a1off + k0] = st;
      }
    }
  }

  f4v acc[2][8];
#pragma unroll
  for (int i = 0; i < 2; ++i)
#pragma unroll
    for (int j = 0; j < 8; ++j) acc[i][j] = (f4v)0.f;

#pragma unroll
  for (int ks = 0; ks < 4; ++ks) {                // MFMA loop: W loads (L2) + 64 MFMA
    int k0 = ks * 32 + quad * 8;
#pragma unroll
    for (int j = 0; j < 8; ++j) {                 // B[k][n=col] for out-tile j = W[j*16+col][k]
      s8v bf = *(const s8v*)&Wbf[(j * 16 + col) * DD + k0];
      acc[0][j] = __builtin_amdgcn_mfma_f32_16x16x32_bf16(af0[ks], bf, acc[0][j], 0, 0, 0);
      acc[1][j] = __builtin_amdgcn_mfma_f32_16x16x32_bf16(af1[ks], bf, acc[1][j], 0, 0, 0);
    }
  }

  float bb[8];
#pragma unroll
  for (int j = 0; j < 8; ++j) bb[j] = bl[j * 16 + col];
#pragma unroll
  for (int i = 0; i < 2; ++i) {
    int rowb = nb + i * 16 + quad * 4;            // D: col=lane&15, row=quad*4+reg
#pragma unroll
    for (int r = 0; r < 4; ++r) {
      int n = rowb + r;
      if (n < NN) {
#pragma unroll
        for (int j = 0; j < 8; ++j)
          hl[(long)n * DD + j * 16 + col] = f2bf(acc[i][j][r] + bb[j]);
      }
    }
  }
}

// ---------- gather-aggregate + self term + BN partials ----------
// EIGHTH-wave (8 lanes) owns a CONTIGUOUS run of FOUR nodes (R18): halves the
// serial chain length and doubles blocks/CU (128 nodes/block, grid 1563).
// Stat reduction via __shfl_xor across the 8 chain slots per wave + tiny 4KB
// LDS cross-wave pass (was 34.8KB -> LDS no longer the residency limiter;
// R17 occupancy was 18% at 3 blocks/CU). Rolling recs prefetch, 2-edge
// unroll, bf16 hl/btc gathers, fp16 pre store -- all unchanged.
__global__ __launch_bounds__(256) void k_aggregate(const ushort* __restrict__ hl,
    const int* __restrict__ off, const int4* __restrict__ recs,
    const ushort* __restrict__ btc, const float* __restrict__ rootl,
    const float* __restrict__ invd, ushort* __restrict__ pre,
    float* __restrict__ gsum, float* __restrict__ gss) {
  __shared__ float redS[4][8][16], redQ[4][8][16]; // 4KB cross-wave buffer
  int t = threadIdx.x;
  int ql = t & 7;                                  // lane within eighth-wave
  int qs = t >> 3;                                 // chain slot 0..31
  int d0 = ql * 16;
  int base = blockIdx.x * 128 + qs * 4;            // 4 nodes per chain
  float rt[16];
#pragma unroll
  for (int j = 0; j < 16; ++j) rt[j] = rootl[d0 + j];
  float sa[16], qa[16];
#pragma unroll
  for (int j = 0; j < 16; ++j) { sa[j] = 0.f; qa[j] = 0.f; }
  if (base < NN) {
    int eptr = off[base];
    int enext = off[base + 1];
    int4 r0 = recs[(eptr < NE) ? eptr : (NE - 1)];           // rolling prefetch regs
    int4 r1 = recs[(eptr + 1 < NE) ? eptr + 1 : (NE - 1)];
#pragma unroll 1
    for (int j = 0; j < 4; ++j) {
      int n = base + j;
      int ia = base + j + 2; if (ia > NN) ia = NN;
      int e_after = off[ia];                       // issued early, used next iter
      int eend = enext;
      s8v sv0 = *(const s8v*)&hl[(long)n * DD + d0];         // self-term (bf16)
      s8v sv1 = *(const s8v*)&hl[(long)n * DD + d0 + 8];
      float iv = invd[n];
      float acc[16];
#pragma unroll
      for (int k = 0; k < 16; ++k) acc[k] = 0.f;
      while (eptr + 2 <= eend) {                   // 2 edges per trip
        int4 ra = r0, rb = r1;
        int p0 = eptr + 2; if (p0 >= NE) p0 = NE - 1;
        int p1 = eptr + 3; if (p1 >= NE) p1 = NE - 1;
        r0 = recs[p0];                             // prefetch next pair
        r1 = recs[p1];
        s8v ha0 = *(const s8v*)&hl[(long)ra.x * DD + d0];    // 32B bf16 gather
        s8v ha1 = *(const s8v*)&hl[(long)ra.x * DD + d0 + 8];
        s8v ea0 = *(const s8v*)&btc[ra.y * DD + d0];         // 32B bf16 btc
        s8v ea1 = *(const s8v*)&btc[ra.y * DD + d0 + 8];
        s8v hb0 = *(const s8v*)&hl[(long)rb.x * DD + d0];
        s8v hb1 = *(const s8v*)&hl[(long)rb.x * DD + d0 + 8];
        s8v eb0 = *(const s8v*)&btc[rb.y * DD + d0];
        s8v eb1 = *(const s8v*)&btc[rb.y * DD + d0 + 8];
        float na = __int_as_float(ra.z);
        float nb = __int_as_float(rb.z);
#pragma unroll
        for (int k = 0; k < 8; ++k) {
          acc[k]     += fmaxf(bf2f((ushort)ha0[k]) + bf2f((ushort)ea0[k]), 0.f) * na
                      + fmaxf(bf2f((ushort)hb0[k]) + bf2f((ushort)eb0[k]), 0.f) * nb;
          acc[8 + k] += fmaxf(bf2f((ushort)ha1[k]) + bf2f((ushort)ea1[k]), 0.f) * na
                      + fmaxf(bf2f((ushort)hb1[k]) + bf2f((ushort)eb1[k]), 0.f) * nb;
        }
        eptr += 2;
      }
      if (eptr < eend) {                           // odd leftover edge
        int4 ra = r0;
        int4 tmp = r1;
        int p0 = eptr + 2; if (p0 >= NE) p0 = NE - 1;
        r1 = recs[p0];                             // maintain rolling invariant
        r0 = tmp;
        s8v hv0 = *(const s8v*)&hl[(long)ra.x * DD + d0];
        s8v hv1 = *(const s8v*)&hl[(long)ra.x * DD + d0 + 8];
        s8v ev0 = *(const s8v*)&btc[ra.y * DD + d0];
        s8v ev1 = *(const s8v*)&btc[ra.y * DD + d0 + 8];
        float nr = __int_as_float(ra.z);
#pragma unroll
        for (int k = 0; k < 8; ++k) {
          acc[k]     += fmaxf(bf2f((ushort)hv0[k]) + bf2f((ushort)ev0[k]), 0.f) * nr;
          acc[8 + k] += fmaxf(bf2f((ushort)hv1[k]) + bf2f((ushort)ev1[k]), 0.f) * nr;
        }
        eptr += 1;
      }
      float pv[16];
#pragma unroll
      for (int k = 0; k < 8; ++k) {
        pv[k]     = acc[k]     + fmaxf(bf2f((ushort)sv0[k]) + rt[k],     0.f) * iv;
        pv[8 + k] = acc[8 + k] + fmaxf(bf2f((ushort)sv1[k]) + rt[8 + k], 0.f) * iv;
      }
      s8v pq0, pq1;                                // pre stored as fp16 (32B)
#pragma unroll
      for (int k = 0; k < 8; ++k) {
        pq0[k] = (short)f2h(pv[k]);
        pq1[k] = (short)f2h(pv[8 + k]);
      }
      *(s8v*)&pre[(long)n * DD + d0] = pq0;
      *(s8v*)&pre[(long)n * DD + d0 + 8] = pq1;
#pragma unroll
      for (int k = 0; k < 16; ++k) {
        sa[k] += pv[k];
        qa[k] += pv[k] * pv[k];
      }
      enext = e_after;
    }
  }
  // wave-level reduce across the 8 chain slots sharing each ql (lanes xor 8/16/32)
#pragma unroll
  for (int k = 0; k < 16; ++k) {
    float s = sa[k], q = qa[k];
    s += __shfl_xor(s, 8);  q += __shfl_xor(q, 8);
    s += __shfl_xor(s, 16); q += __shfl_xor(q, 16);
    s += __shfl_xor(s, 32); q += __shfl_xor(q, 32);
    sa[k] = s; qa[k] = q;
  }
  int wv = t >> 6, lane = t & 63;
  if (lane < 8) {                                  // one writer per (wave, ql)
#pragma unroll
    for (int k = 0; k < 16; ++k) { redS[wv][ql][k] = sa[k]; redQ[wv][ql][k] = qa[k]; }
  }
  __syncthreads();
  if (t < 128) {                                   // d = t; ql=d>>4, c=d&15
    int qq = t >> 4, c = t & 15;
    float S = redS[0][qq][c] + redS[1][qq][c] + redS[2][qq][c] + redS[3][qq][c];
    float Q = redQ[0][qq][c] + redQ[1][qq][c] + redQ[2][qq][c] + redQ[3][qq][c];
    atomicAdd(&gsum[t], S);
    atomicAdd(&gss[t], Q);
  }
}

// ---------- final: out = (h+act0) + act1 + act2 + act3 + (pre4*scale4 + shift4)
// Pure write of out; scale4/shift4 computed in-kernel; pre4 read as fp16. ----------
__global__ __launch_bounds__(256) void k_apply_final(const ushort* __restrict__ preh,
    const ushort* __restrict__ acts, const float* __restrict__ gsum,
    const float* __restrict__ gss, const float* __restrict__ gmm,
    const float* __restrict__ bbn, float* __restrict__ out) {
  __shared__ float s_sc[DD], s_sh[DD];
  const int NDH = NN * DD / 2;                    // uint elements per slot
  int t = threadIdx.x;
  if (t < DD) {
    float m = gsum[t] * (1.0f / NN);
    float v = gss[t] * (1.0f / NN) - m * m;
    float sc = gmm[t] * rsqrtf(v + EPSV);
    s_sc[t] = sc;
    s_sh[t] = bbn[t] - m * sc;
  }
  __syncthreads();
  int idx = blockIdx.x * 256 + t;                 // N*D/2 exact
  int dp = idx & 63;
  uint a0 = ((const uint*)acts)[idx];
  uint a1 = ((const uint*)acts)[idx + NDH];
  uint a2 = ((const uint*)acts)[idx + 2 * NDH];
  uint a3 = ((const uint*)acts)[idx + 3 * NDH];
  uint pv = ((const uint*)preh)[idx];
  float2 o;
  o.x = bf2f((ushort)a0) + bf2f((ushort)a1) + bf2f((ushort)a2) + bf2f((ushort)a3)
      + h2f((ushort)pv) * s_sc[dp * 2] + s_sh[dp * 2];
  o.y = bf2f((ushort)(a0 >> 16)) + bf2f((ushort)(a1 >> 16)) + bf2f((ushort)(a2 >> 16))
      + bf2f((ushort)(a3 >> 16))
      + h2f((ushort)(pv >> 16)) * s_sc[dp * 2 + 1] + s_sh[dp * 2 + 1];
  *(float2*)&out[idx * 2] = o;
}

extern "C" void kernel_launch(void* const* d_in, const int* in_sizes, int n_in,
                              void* d_out, int out_size, void* d_ws, size_t ws_size,
                              hipStream_t stream) {
  const int*   x     = (const int*)d_in[0];
  const int*   ei    = (const int*)d_in[1];
  const int*   ea    = (const int*)d_in[2];
  const float* at    = (const float*)d_in[3];
  const float* bt    = (const float*)d_in[4];
  const float* W     = (const float*)d_in[5];
  const float* b     = (const float*)d_in[6];
  const float* root  = (const float*)d_in[7];
  const float* gamma = (const float*)d_in[8];
  const float* beta  = (const float*)d_in[9];
  float* out = (float*)d_out;

  char* ws = (char*)d_ws;
  size_t ND = (size_t)NN * DD;
  ushort* hl   = (ushort*)ws;                       // ND bf16
  ushort* pre  = hl + ND;                           // ND fp16
  ushort* acts = pre + ND;                          // 4*ND bf16; slot0: h then h+act0
  int4*   recs = (int4*)(acts + 4 * ND);            // NE * 16B (byte off 12*ND, 16B-aligned)
  ushort* Wbf  = (ushort*)(recs + NE);              // 5*128*128 bf16
  ushort* btc  = Wbf + NL * DD * DD;                // 1000*128 bf16 (256 KB)
  float*  deg  = (float*)(btc + 1000 * DD);         // N
  float*  dis  = deg + NN;                          // N
  float*  invd = dis + NN;                          // N
  int*    cnt  = (int*)(invd + NN);                 // N
  int*    offa = cnt + NN;                          // N+1 (+3 pad)
  int*    nxt  = offa + NN + 4;                     // N
  int*    bsum = nxt + NN;                          // 256
  int*    bbase= bsum + 256;                        // 256
  float*  gsum = (float*)(bbase + 256);             // NL*D (per-layer slices)
  float*  gss  = gsum + NL * DD;                    // NL*D
  ushort* atb  = (ushort*)(gss + NL * DD);          // 9*100*128 bf16 (230 KB)

  // ---- precompute ----
  hipMemsetAsync(gsum, 0, 2 * NL * DD * sizeof(float), stream);  // all stat slices
  k_deg_init<<<(NN + 255) / 256, 256, 0, stream>>>(deg, cnt);
  k_deg_count<<<(NE + 255) / 256, 256, 0, stream>>>(ei, deg, cnt);
  k_deg_fin<<<(NN + 255) / 256, 256, 0, stream>>>(deg, dis, invd);
  k_scan1<<<SCAN_BLKS, 256, 0, stream>>>(cnt, offa, bsum);
  k_scan2<<<1, 256, 0, stream>>>(bsum, bbase);
  k_scan3<<<(NN + 255) / 256, 256, 0, stream>>>(offa, bbase, nxt);
  k_fill<<<(NE + 255) / 256, 256, 0, stream>>>(ei, ea, dis, nxt, recs);
  k_btc<<<1000 * DD / 256, 256, 0, stream>>>(bt, btc);
  k_wconv<<<NL * DD * DD / 256, 256, 0, stream>>>(W, Wbf);
  k_atc<<<9 * AV * DD / 256, 256, 0, stream>>>(at, atb);
  k_encode<<<NN * 32 / 256, 256, 0, stream>>>(x, atb, acts);

  // ---- layers ----
  for (int l = 0; l < NL; ++l) {
    int mode = (l == 0) ? 0 : ((l == 1) ? 2 : 1);
    int lp = (l == 0) ? 0 : l - 1;                 // previous layer's stat slice
    k_gemm<<<(NN + 127) / 128, 256, 0, stream>>>(
        acts, pre, Wbf + (size_t)l * DD * DD, b + l * DD,
        gsum + (size_t)lp * DD, gss + (size_t)lp * DD,
        gamma + (size_t)lp * DD, beta + (size_t)lp * DD,
        acts + (size_t)(l == 0 ? 0 : l - 1) * ND,
        hl, mode);
    k_aggregate<<<(NN + 127) / 128, 256, 0, stream>>>(hl, offa, recs, btc,
        root + l * DD, invd, pre, gsum + (size_t)l * DD, gss + (size_t)l * DD);
  }
  k_apply_final<<<(int)(ND / 2 / 256), 256, 0, stream>>>(pre, acts,
      gsum + 4 * DD, gss + 4 * DD, gamma + 4 * DD, beta + 4 * DD, out);
}

// Round 19
// 886.432 us; speedup vs baseline: 1.0379x; 1.0379x over previous
//
#include <hip/hip_runtime.h>
#include <hip/hip_fp16.h>

#define NN 200000
#define NE 400000
#define DD 128
#define NL 5
#define AV 100
#define BV 10
#define EPSV 1e-5f
#define SCAN_BLKS 196   // ceil(NN/1024)

typedef short s8v __attribute__((ext_vector_type(8)));   // 8 bf16/fp16 (4 VGPRs)
typedef float f4v __attribute__((ext_vector_type(4)));   // 4 fp32 acc

__device__ __forceinline__ ushort f2bf(float f) {        // RNE float->bf16
  uint u = __float_as_uint(f);
  u += 0x7FFFu + ((u >> 16) & 1u);
  return (ushort)(u >> 16);
}

__device__ __forceinline__ float bf2f(ushort u) {        // bf16->float
  return __uint_as_float(((uint)u) << 16);
}

__device__ __forceinline__ ushort f2h(float f) {         // RNE float->fp16
  return __half_as_ushort(__float2half(f));
}

__device__ __forceinline__ float h2f(ushort u) {         // fp16->float
  return __half2float(__ushort_as_half(u));
}

// ---------- fused table conversions (R19: was 3 launches) ----------
// [0, 115200): atom table -> bf16
// [115200, 197120): W -> bf16
// [197120, 325120): combined bond table -> bf16
__global__ __launch_bounds__(256) void k_tables(const float* __restrict__ at,
    const float* __restrict__ W, const float* __restrict__ bt,
    ushort* __restrict__ atb, ushort* __restrict__ Wbf, ushort* __restrict__ btc) {
  int i = blockIdx.x * 256 + threadIdx.x;         // 325120 threads exact (1270 blocks)
  if (i < 9 * AV * DD) {
    atb[i] = f2bf(at[i]);
  } else if (i < 9 * AV * DD + NL * DD * DD) {
    int j = i - 9 * AV * DD;
    Wbf[j] = f2bf(W[j]);
  } else {
    int j = i - 9 * AV * DD - NL * DD * DD;       // < 1000*128
    int p = j >> 7, d = j & 127;
    int a = p % 10, b2 = (p / 10) % 10, c = p / 100;
    btc[j] = f2bf(bt[(0 * BV + a) * DD + d] + bt[(1 * BV + b2) * DD + d]
                + bt[(2 * BV + c) * DD + d]);
  }
}

// ---------- encode: h = sum of atom embeddings -> acts slot 0 (bf16) ----------
// HALF-wave (32 lanes) per node, 4 dims/lane via ushort4 (8B) gathers from the
// bf16 table.
__global__ __launch_bounds__(256) void k_encode(const int* __restrict__ x,
    const ushort* __restrict__ atb, ushort* __restrict__ hbuf) {
  int idx = blockIdx.x * 256 + threadIdx.x;       // N*32 threads: grid 25000 exact
  int n = idx >> 5, dp = idx & 31;                // half-wave = one node
  const int* xr = x + n * 9;
  float s0 = 0.f, s1 = 0.f, s2 = 0.f, s3 = 0.f;
#pragma unroll
  for (int c = 0; c < 9; ++c) {
    ushort4 v = *(const ushort4*)&atb[(c * AV + xr[c]) * DD + dp * 4];
    s0 += bf2f(v.x); s1 += bf2f(v.y); s2 += bf2f(v.z); s3 += bf2f(v.w);
  }
  ushort4 o;
  o.x = f2bf(s0); o.y = f2bf(s1); o.z = f2bf(s2); o.w = f2bf(s3);
  *(ushort4*)&hbuf[(long)n * DD + dp * 4] = o;
}

// ---------- degree ----------
__global__ __launch_bounds__(256) void k_deg_init(float* __restrict__ deg,
                                                  int* __restrict__ cnt) {
  int i = blockIdx.x * 256 + threadIdx.x;
  if (i < NN) { deg[i] = 1.0f; cnt[i] = 0; }
}

__global__ __launch_bounds__(256) void k_deg_count(const int* __restrict__ ei,
    float* __restrict__ deg, int* __restrict__ cnt) {
  int e = blockIdx.x * 256 + threadIdx.x;
  if (e < NE) {
    atomicAdd(&deg[ei[e]], 1.0f);
    atomicAdd(&cnt[ei[NE + e]], 1);
  }
}

// ---------- exclusive scan of cnt -> off ----------
__global__ __launch_bounds__(256) void k_scan1(const int* __restrict__ cnt,
    int* __restrict__ off, int* __restrict__ bsum) {
  __shared__ int s[256];
  int t = threadIdx.x;
  int base = blockIdx.x * 1024 + t * 4;
  int c0 = (base + 0 < NN) ? cnt[base + 0] : 0;
  int c1 = (base + 1 < NN) ? cnt[base + 1] : 0;
  int c2 = (base + 2 < NN) ? cnt[base + 2] : 0;
  int c3 = (base + 3 < NN) ? cnt[base + 3] : 0;
  int tsum = c0 + c1 + c2 + c3;
  s[t] = tsum;
  __syncthreads();
  for (int o = 1; o < 256; o <<= 1) {
    int v = (t >= o) ? s[t - o] : 0;
    __syncthreads();
    s[t] += v;
    __syncthreads();
  }
  int excl = s[t] - tsum;
  if (base + 0 < NN) off[base + 0] = excl;
  if (base + 1 < NN) off[base + 1] = excl + c0;
  if (base + 2 < NN) off[base + 2] = excl + c0 + c1;
  if (base + 3 < NN) off[base + 3] = excl + c0 + c1 + c2;
  if (t == 255) bsum[blockIdx.x] = s[255];
}

__global__ __launch_bounds__(256) void k_scan2(const int* __restrict__ bsum,
    int* __restrict__ bbase) {
  __shared__ int s[256];
  int t = threadIdx.x;
  int v0 = (t < SCAN_BLKS) ? bsum[t] : 0;
  s[t] = v0;
  __syncthreads();
  for (int o = 1; o < 256; o <<= 1) {
    int v = (t >= o) ? s[t - o] : 0;
    __syncthreads();
    s[t] += v;
    __syncthreads();
  }
  if (t < SCAN_BLKS) bbase[t] = s[t] - v0;
}

// ---------- scan finalize + degree finalize (R19: deg_fin folded in) ----------
__global__ __launch_bounds__(256) void k_scan3(int* __restrict__ off,
    const int* __restrict__ bbase, int* __restrict__ nxt,
    const float* __restrict__ deg, float* __restrict__ dis,
    float* __restrict__ invd) {
  int i = blockIdx.x * 256 + threadIdx.x;
  if (i < NN) {
    int v = off[i] + bbase[i >> 10];
    off[i] = v;
    nxt[i] = v;
    float dg = deg[i];
    dis[i] = rsqrtf(dg);
    invd[i] = 1.0f / dg;
  }
  if (i == 0) off[NN] = NE;
}

// ---------- fill CSR records: {row, packed_ea, norm_bits, 0} ----------
__global__ __launch_bounds__(256) void k_fill(const int* __restrict__ ei,
    const int* __restrict__ ea, const float* __restrict__ dis,
    int* __restrict__ nxt, int4* __restrict__ recs) {
  int e = blockIdx.x * 256 + threadIdx.x;
  if (e >= NE) return;
  int r = ei[e], c = ei[NE + e];
  int pa = ea[e * 3 + 0] + ea[e * 3 + 1] * 10 + ea[e * 3 + 2] * 100;
  float nr = dis[r] * dis[c];
  int pos = atomicAdd(&nxt[c], 1);
  recs[pos] = make_int4(r, pa, __float_as_int(nr), 0);
}

// ---------- MFMA GEMM: hl(BF16) = A' @ Wl^T + bl ----------
// mode0: A' = srcbf (bf16 h from encode, = acts slot 0).
// mode1: A' = relu(pre_fp16*scale+shift); A' (bf16) stored to actl.
// mode2: like mode1 but folds the h still in actl: store bf16(h + A').
// pre is FP16; BN fold in-kernel from the PREVIOUS layer's stat slice.
__global__ __launch_bounds__(256) void k_gemm(const ushort* __restrict__ srcbf,
    const ushort* __restrict__ srcp, const ushort* __restrict__ Wbf,
    const float* __restrict__ bl, const float* __restrict__ gsum,
    const float* __restrict__ gss, const float* __restrict__ gmm,
    const float* __restrict__ bbn, ushort* __restrict__ actl,
    ushort* __restrict__ hl, int mode) {
  __shared__ float s_sc[DD], s_sh[DD];
  int t = threadIdx.x;
  int lane = t & 63, wave = t >> 6;
  int col = lane & 15, quad = lane >> 4;
  int nb = blockIdx.x * 128 + wave * 32;
  int r0 = nb + col, r1 = nb + 16 + col;
  bool v0 = r0 < NN, v1 = r1 < NN;
  long a0off = (long)(v0 ? r0 : NN - 1) * DD;
  long a1off = (long)(v1 ? r1 : NN - 1) * DD;

  s8v af0[4], af1[4];                             // A fragments, 4 k-slices

  if (mode == 0) {
#pragma unroll
    for (int ks = 0; ks < 4; ++ks) {              // 8 loads, one burst
      int k0 = ks * 32 + quad * 8;
      af0[ks] = *(const s8v*)&srcbf[a0off + k0];
      af1[ks] = *(const s8v*)&srcbf[a1off + k0];
    }
  } else {
    if (t < DD) {                                 // BN fold: stats -> scale/shift
      float m = gsum[t] * (1.0f / NN);
      float v = gss[t] * (1.0f / NN) - m * m;
      float sc = gmm[t] * rsqrtf(v + EPSV);
      s_sc[t] = sc;
      s_sh[t] = bbn[t] - m * sc;
    }
    __syncthreads();
    s8v pF0[4], pF1[4];                           // fp16 pre, one burst (8 loads)
#pragma unroll
    for (int ks = 0; ks < 4; ++ks) {
      int k0 = ks * 32 + quad * 8;
      pF0[ks] = *(const s8v*)&srcp[a0off + k0];
      pF1[ks] = *(const s8v*)&srcp[a1off + k0];
    }
#pragma unroll
    for (int ks = 0; ks < 4; ++ks) {              // activation + pack (VALU)
      int k0 = ks * 32 + quad * 8;
      float scv[8], shv[8];
#pragma unroll
      for (int j = 0; j < 8; ++j) { scv[j] = s_sc[k0 + j]; shv[j] = s_sh[k0 + j]; }
#pragma unroll
      for (int j = 0; j < 8; ++j) {
        float w = fmaxf(h2f((ushort)pF0[ks][j]) * scv[j] + shv[j], 0.f);
        af0[ks][j] = (short)f2bf(w);
        float u = fmaxf(h2f((ushort)pF1[ks][j]) * scv[j] + shv[j], 0.f);
        af1[ks][j] = (short)f2bf(u);
      }
    }
    // store A' (bf16); mode2 folds the h currently in actl
    if (v0) {
#pragma unroll
      for (int ks = 0; ks < 4; ++ks) {
        int k0 = ks * 32 + quad * 8;
        s8v st = af0[ks];
        if (mode == 2) {
          s8v h8 = *(const s8v*)&actl[a0off + k0];
#pragma unroll
          for (int j = 0; j < 8; ++j)
            st[j] = (short)f2bf(bf2f((ushort)h8[j]) + bf2f((ushort)af0[ks][j]));
        }
        *(s8v*)&actl[a0off + k0] = st;
      }
    }
    if (v1) {
#pragma unroll
      for (int ks = 0; ks < 4; ++ks) {
        int k0 = ks * 32 + quad * 8;
        s8v st = af1[ks];
        if (mode == 2) {
          s8v h8 = *(const s8v*)&actl[a1off + k0];
#pragma unroll
          for (int j = 0; j < 8; ++j)
            st[j] = (short)f2bf(bf2f((ushort)h8[j]) + bf2f((ushort)af1[ks][j]));
        }
        *(s8v*)&actl[a1off + k0] = st;
      }
    }
  }

  f4v acc[2][8];
#pragma unroll
  for (int i = 0; i < 2; ++i)
#pragma unroll
    for (int j = 0; j < 8; ++j) acc[i][j] = (f4v)0.f;

#pragma unroll
  for (int ks = 0; ks < 4; ++ks) {                // MFMA loop: W loads (L2) + 64 MFMA
    int k0 = ks * 32 + quad * 8;
#pragma unroll
    for (int j = 0; j < 8; ++j) {                 // B[k][n=col] for out-tile j = W[j*16+col][k]
      s8v bf = *(const s8v*)&Wbf[(j * 16 + col) * DD + k0];
      acc[0][j] = __builtin_amdgcn_mfma_f32_16x16x32_bf16(af0[ks], bf, acc[0][j], 0, 0, 0);
      acc[1][j] = __builtin_amdgcn_mfma_f32_16x16x32_bf16(af1[ks], bf, acc[1][j], 0, 0, 0);
    }
  }

  float bb[8];
#pragma unroll
  for (int j = 0; j < 8; ++j) bb[j] = bl[j * 16 + col];
#pragma unroll
  for (int i = 0; i < 2; ++i) {
    int rowb = nb + i * 16 + quad * 4;            // D: col=lane&15, row=quad*4+reg
#pragma unroll
    for (int r = 0; r < 4; ++r) {
      int n = rowb + r;
      if (n < NN) {
#pragma unroll
        for (int j = 0; j < 8; ++j)
          hl[(long)n * DD + j * 16 + col] = f2bf(acc[i][j][r] + bb[j]);
      }
    }
  }
}

// ---------- gather-aggregate + self term + BN partials (R17 body, reverted) ----------
// EIGHTH-wave (8 lanes) owns a CONTIGUOUS run of 8 nodes: lane covers
// d = (lane&7)*16 .. +15 (32B bf16 gathers; bf16 btc). Block = 256 nodes,
// grid 782. Rolling 2-record recs prefetch, 2-edge unroll, fp16 pre store.
// R18's 4-node chains + shuffle reduce REGRESSED (75 vs 69 us: per-chain
// setup amortization halved, +96 VALU shuffle ops; occupancy was grid-capped
// not LDS-capped) -- reverted to this exact structure.
__global__ __launch_bounds__(256) void k_aggregate(const ushort* __restrict__ hl,
    const int* __restrict__ off, const int4* __restrict__ recs,
    const ushort* __restrict__ btc, const float* __restrict__ rootl,
    const float* __restrict__ invd, ushort* __restrict__ pre,
    float* __restrict__ gsum, float* __restrict__ gss) {
  __shared__ float redS[256][17], redQ[256][17];   // +1 pad: conflict-free
  int t = threadIdx.x;
  int ql = t & 7;                                  // lane within eighth-wave
  int qs = t >> 3;                                 // chain slot 0..31
  int d0 = ql * 16;
  int base = blockIdx.x * 256 + qs * 8;
  float rt[16];
#pragma unroll
  for (int j = 0; j < 16; ++j) rt[j] = rootl[d0 + j];
  float sa[16], qa[16];
#pragma unroll
  for (int j = 0; j < 16; ++j) { sa[j] = 0.f; qa[j] = 0.f; }
  if (base < NN) {
    int eptr = off[base];
    int enext = off[base + 1];
    int4 r0 = recs[(eptr < NE) ? eptr : (NE - 1)];           // rolling prefetch regs
    int4 r1 = recs[(eptr + 1 < NE) ? eptr + 1 : (NE - 1)];
#pragma unroll 1
    for (int j = 0; j < 8; ++j) {
      int n = base + j;
      int ia = base + j + 2; if (ia > NN) ia = NN;
      int e_after = off[ia];                       // issued early, used next iter
      int eend = enext;
      s8v sv0 = *(const s8v*)&hl[(long)n * DD + d0];         // self-term (bf16)
      s8v sv1 = *(const s8v*)&hl[(long)n * DD + d0 + 8];
      float iv = invd[n];
      float acc[16];
#pragma unroll
      for (int k = 0; k < 16; ++k) acc[k] = 0.f;
      while (eptr + 2 <= eend) {                   // 2 edges per trip
        int4 ra = r0, rb = r1;
        int p0 = eptr + 2; if (p0 >= NE) p0 = NE - 1;
        int p1 = eptr + 3; if (p1 >= NE) p1 = NE - 1;
        r0 = recs[p0];                             // prefetch next pair
        r1 = recs[p1];
        s8v ha0 = *(const s8v*)&hl[(long)ra.x * DD + d0];    // 32B bf16 gather
        s8v ha1 = *(const s8v*)&hl[(long)ra.x * DD + d0 + 8];
        s8v ea0 = *(const s8v*)&btc[ra.y * DD + d0];         // 32B bf16 btc
        s8v ea1 = *(const s8v*)&btc[ra.y * DD + d0 + 8];
        s8v hb0 = *(const s8v*)&hl[(long)rb.x * DD + d0];
        s8v hb1 = *(const s8v*)&hl[(long)rb.x * DD + d0 + 8];
        s8v eb0 = *(const s8v*)&btc[rb.y * DD + d0];
        s8v eb1 = *(const s8v*)&btc[rb.y * DD + d0 + 8];
        float na = __int_as_float(ra.z);
        float nb = __int_as_float(rb.z);
#pragma unroll
        for (int k = 0; k < 8; ++k) {
          acc[k]     += fmaxf(bf2f((ushort)ha0[k]) + bf2f((ushort)ea0[k]), 0.f) * na
                      + fmaxf(bf2f((ushort)hb0[k]) + bf2f((ushort)eb0[k]), 0.f) * nb;
          acc[8 + k] += fmaxf(bf2f((ushort)ha1[k]) + bf2f((ushort)ea1[k]), 0.f) * na
                      + fmaxf(bf2f((ushort)hb1[k]) + bf2f((ushort)eb1[k]), 0.f) * nb;
        }
        eptr += 2;
      }
      if (eptr < eend) {                           // odd leftover edge
        int4 ra = r0;
        int4 tmp = r1;
        int p0 = eptr + 2; if (p0 >= NE) p0 = NE - 1;
        r1 = recs[p0];                             // maintain rolling invariant
        r0 = tmp;
        s8v hv0 = *(const s8v*)&hl[(long)ra.x * DD + d0];
        s8v hv1 = *(const s8v*)&hl[(long)ra.x * DD + d0 + 8];
        s8v ev0 = *(const s8v*)&btc[ra.y * DD + d0];
        s8v ev1 = *(const s8v*)&btc[ra.y * DD + d0 + 8];
        float nr = __int_as_float(ra.z);
#pragma unroll
        for (int k = 0; k < 8; ++k) {
          acc[k]     += fmaxf(bf2f((ushort)hv0[k]) + bf2f((ushort)ev0[k]), 0.f) * nr;
          acc[8 + k] += fmaxf(bf2f((ushort)hv1[k]) + bf2f((ushort)ev1[k]), 0.f) * nr;
        }
        eptr += 1;
      }
      float pv[16];
#pragma unroll
      for (int k = 0; k < 8; ++k) {
        pv[k]     = acc[k]     + fmaxf(bf2f((ushort)sv0[k]) + rt[k],     0.f) * iv;
        pv[8 + k] = acc[8 + k] + fmaxf(bf2f((ushort)sv1[k]) + rt[8 + k], 0.f) * iv;
      }
      s8v pq0, pq1;                                // pre stored as fp16 (32B)
#pragma unroll
      for (int k = 0; k < 8; ++k) {
        pq0[k] = (short)f2h(pv[k]);
        pq1[k] = (short)f2h(pv[8 + k]);
      }
      *(s8v*)&pre[(long)n * DD + d0] = pq0;
      *(s8v*)&pre[(long)n * DD + d0 + 8] = pq1;
#pragma unroll
      for (int k = 0; k < 16; ++k) {
        sa[k] += pv[k];
        qa[k] += pv[k] * pv[k];
      }
      enext = e_after;
    }
  }
#pragma unroll
  for (int k = 0; k < 16; ++k) { redS[t][k] = sa[k]; redQ[t][k] = qa[k]; }
  __syncthreads();
  if (t < 128) {                                   // d = t; ql=d>>4, c=d&15
    int qq = t >> 4, c = t & 15;
    float S = 0.f, Q = 0.f;
#pragma unroll
    for (int h = 0; h < 32; ++h) {
      S += redS[h * 8 + qq][c];
      Q += redQ[h * 8 + qq][c];
    }
    atomicAdd(&gsum[t], S);
    atomicAdd(&gss[t], Q);
  }
}

// ---------- final: out = (h+act0) + act1 + act2 + act3 + (pre4*scale4 + shift4)
// Pure write of out; scale4/shift4 computed in-kernel; pre4 read as fp16. ----------
__global__ __launch_bounds__(256) void k_apply_final(const ushort* __restrict__ preh,
    const ushort* __restrict__ acts, const float* __restrict__ gsum,
    const float* __restrict__ gss, const float* __restrict__ gmm,
    const float* __restrict__ bbn, float* __restrict__ out) {
  __shared__ float s_sc[DD], s_sh[DD];
  const int NDH = NN * DD / 2;                    // uint elements per slot
  int t = threadIdx.x;
  if (t < DD) {
    float m = gsum[t] * (1.0f / NN);
    float v = gss[t] * (1.0f / NN) - m * m;
    float sc = gmm[t] * rsqrtf(v + EPSV);
    s_sc[t] = sc;
    s_sh[t] = bbn[t] - m * sc;
  }
  __syncthreads();
  int idx = blockIdx.x * 256 + t;                 // N*D/2 exact
  int dp = idx & 63;
  uint a0 = ((const uint*)acts)[idx];
  uint a1 = ((const uint*)acts)[idx + NDH];
  uint a2 = ((const uint*)acts)[idx + 2 * NDH];
  uint a3 = ((const uint*)acts)[idx + 3 * NDH];
  uint pv = ((const uint*)preh)[idx];
  float2 o;
  o.x = bf2f((ushort)a0) + bf2f((ushort)a1) + bf2f((ushort)a2) + bf2f((ushort)a3)
      + h2f((ushort)pv) * s_sc[dp * 2] + s_sh[dp * 2];
  o.y = bf2f((ushort)(a0 >> 16)) + bf2f((ushort)(a1 >> 16)) + bf2f((ushort)(a2 >> 16))
      + bf2f((ushort)(a3 >> 16))
      + h2f((ushort)(pv >> 16)) * s_sc[dp * 2 + 1] + s_sh[dp * 2 + 1];
  *(float2*)&out[idx * 2] = o;
}

extern "C" void kernel_launch(void* const* d_in, const int* in_sizes, int n_in,
                              void* d_out, int out_size, void* d_ws, size_t ws_size,
                              hipStream_t stream) {
  const int*   x     = (const int*)d_in[0];
  const int*   ei    = (const int*)d_in[1];
  const int*   ea    = (const int*)d_in[2];
  const float* at    = (const float*)d_in[3];
  const float* bt    = (const float*)d_in[4];
  const float* W     = (const float*)d_in[5];
  const float* b     = (const float*)d_in[6];
  const float* root  = (const float*)d_in[7];
  const float* gamma = (const float*)d_in[8];
  const float* beta  = (const float*)d_in[9];
  float* out = (float*)d_out;

  char* ws = (char*)d_ws;
  size_t ND = (size_t)NN * DD;
  ushort* hl   = (ushort*)ws;                       // ND bf16
  ushort* pre  = hl + ND;                           // ND fp16
  ushort* acts = pre + ND;                          // 4*ND bf16; slot0: h then h+act0
  int4*   recs = (int4*)(acts + 4 * ND);            // NE * 16B (byte off 12*ND, 16B-aligned)
  ushort* Wbf  = (ushort*)(recs + NE);              // 5*128*128 bf16
  ushort* btc  = Wbf + NL * DD * DD;                // 1000*128 bf16 (256 KB)
  float*  deg  = (float*)(btc + 1000 * DD);         // N
  float*  dis  = deg + NN;                          // N
  float*  invd = dis + NN;                          // N
  int*    cnt  = (int*)(invd + NN);                 // N
  int*    offa = cnt + NN;                          // N+1 (+3 pad)
  int*    nxt  = offa + NN + 4;                     // N
  int*    bsum = nxt + NN;                          // 256
  int*    bbase= bsum + 256;                        // 256
  float*  gsum = (float*)(bbase + 256);             // NL*D (per-layer slices)
  float*  gss  = gsum + NL * DD;                    // NL*D
  ushort* atb  = (ushort*)(gss + NL * DD);          // 9*100*128 bf16 (230 KB)

  // ---- precompute ----
  hipMemsetAsync(gsum, 0, 2 * NL * DD * sizeof(float), stream);  // all stat slices
  k_deg_init<<<(NN + 255) / 256, 256, 0, stream>>>(deg, cnt);
  k_deg_count<<<(NE + 255) / 256, 256, 0, stream>>>(ei, deg, cnt);
  k_scan1<<<SCAN_BLKS, 256, 0, stream>>>(cnt, offa, bsum);
  k_scan2<<<1, 256, 0, stream>>>(bsum, bbase);
  k_scan3<<<(NN + 255) / 256, 256, 0, stream>>>(offa, bbase, nxt, deg, dis, invd);
  k_fill<<<(NE + 255) / 256, 256, 0, stream>>>(ei, ea, dis, nxt, recs);
  k_tables<<<(9 * AV * DD + NL * DD * DD + 1000 * DD) / 256, 256, 0, stream>>>(
      at, W, bt, atb, Wbf, btc);
  k_encode<<<NN * 32 / 256, 256, 0, stream>>>(x, atb, acts);

  // ---- layers ----
  for (int l = 0; l < NL; ++l) {
    int mode = (l == 0) ? 0 : ((l == 1) ? 2 : 1);
    int lp = (l == 0) ? 0 : l - 1;                 // previous layer's stat slice
    k_gemm<<<(NN + 127) / 128, 256, 0, stream>>>(
        acts, pre, Wbf + (size_t)l * DD * DD, b + l * DD,
        gsum + (size_t)lp * DD, gss + (size_t)lp * DD,
        gamma + (size_t)lp * DD, beta + (size_t)lp * DD,
        acts + (size_t)(l == 0 ? 0 : l - 1) * ND,
        hl, mode);
    k_aggregate<<<(NN + 255) / 256, 256, 0, stream>>>(hl, offa, recs, btc,
        root + l * DD, invd, pre, gsum + (size_t)l * DD, gss + (size_t)l * DD);
  }
  k_apply_final<<<(int)(ND / 2 / 256), 256, 0, stream>>>(pre, acts,
      gsum + 4 * DD, gss + 4 * DD, gamma + 4 * DD, beta + 4 * DD, out);
}